// Round 4
// baseline (1366.409 us; speedup 1.0000x reference)
//
#include <hip/hip_runtime.h>

// ---------------------------------------------------------------------------
// LlamaDecoderLayer forward on MI355X (gfx950).
// B=4, L=1024, D=2048, H=16, I=8192, DH=128.
// Outputs (f32): out (B,L,D) then attn (B,H,L,L), concatenated in d_out.
// ---------------------------------------------------------------------------

typedef __bf16 bf16;
typedef __bf16 bf16x8 __attribute__((ext_vector_type(8)));
typedef __bf16 bf16x4 __attribute__((ext_vector_type(4)));
typedef float  f32x4  __attribute__((ext_vector_type(4)));

constexpr int   kB  = 4;
constexpr int   kL  = 1024;
constexpr int   kD  = 2048;
constexpr int   kH  = 16;
constexpr int   kI  = 8192;
constexpr int   kDH = 128;
constexpr int   kQKV = 3 * kD;  // 6144
constexpr float kEps = 1e-6f;
constexpr float kScoreScale = 0.08838834764831845f; // 1/sqrt(128)

typedef __attribute__((address_space(1))) void gvoid_t;
typedef __attribute__((address_space(3))) void lvoid_t;

// async global->LDS, 16B per lane; LDS dest linear in lane order.
// Keep ADJACENT LANES on ADJACENT GLOBAL ADDRESSES (round-2 lesson: permuted
// sources quadruple TA transactions and throttle the DMA).
__device__ __forceinline__ void gload_lds16(const void* g, void* l) {
  __builtin_amdgcn_global_load_lds((gvoid_t*)g, (lvoid_t*)l, 16, 0, 0);
}

// ---------------------------------------------------------------------------
// f32 -> bf16 cast (vectorized). n must be a multiple of 4.
// ---------------------------------------------------------------------------
__global__ __launch_bounds__(256) void cast_f32_bf16_kernel(
    const float* __restrict__ x, bf16* __restrict__ y, long n) {
  long i = ((long)blockIdx.x * 256 + threadIdx.x) * 4;
  long stride = (long)gridDim.x * 256 * 4;
  for (; i < n; i += stride) {
    const float4 v = *reinterpret_cast<const float4*>(x + i);
    bf16x4 o;
    o[0] = (bf16)v.x; o[1] = (bf16)v.y; o[2] = (bf16)v.z; o[3] = (bf16)v.w;
    *reinterpret_cast<bf16x4*>(y + i) = o;
  }
}

// ---------------------------------------------------------------------------
// RMSNorm: one block per row of D=2048 f32; writes bf16 (row stride kD).
// ---------------------------------------------------------------------------
__global__ __launch_bounds__(256) void rmsnorm_kernel(
    const float* __restrict__ x, const float* __restrict__ w,
    bf16* __restrict__ out) {
  const long row = blockIdx.x;
  const float* xr = x + row * (long)kD;
  bf16* orow = out + row * (long)kD;
  const int t = threadIdx.x;

  float4 v0 = *(const float4*)(xr + t * 8);
  float4 v1 = *(const float4*)(xr + t * 8 + 4);
  float ss = v0.x * v0.x + v0.y * v0.y + v0.z * v0.z + v0.w * v0.w +
             v1.x * v1.x + v1.y * v1.y + v1.z * v1.z + v1.w * v1.w;

  __shared__ float red[4];
  for (int off = 32; off > 0; off >>= 1) ss += __shfl_down(ss, off);
  if ((t & 63) == 0) red[t >> 6] = ss;
  __syncthreads();
  const float tot = red[0] + red[1] + red[2] + red[3];
  const float rs = rsqrtf(tot / (float)kD + kEps);

  float4 w0 = *(const float4*)(w + t * 8);
  float4 w1 = *(const float4*)(w + t * 8 + 4);
  bf16x8 o;
  o[0] = (bf16)(v0.x * rs * w0.x); o[1] = (bf16)(v0.y * rs * w0.y);
  o[2] = (bf16)(v0.z * rs * w0.z); o[3] = (bf16)(v0.w * rs * w0.w);
  o[4] = (bf16)(v1.x * rs * w1.x); o[5] = (bf16)(v1.y * rs * w1.y);
  o[6] = (bf16)(v1.z * rs * w1.z); o[7] = (bf16)(v1.w * rs * w1.w);
  *(bf16x8*)(orow + t * 8) = o;
}

// ---------------------------------------------------------------------------
// RoPE in-place on qkv buffer (bf16, rows = B*L, ld = 6144; q col 0, k col
// 2048; v untouched).
// ---------------------------------------------------------------------------
__global__ __launch_bounds__(256) void rope_kernel(
    bf16* __restrict__ qkv, const float* __restrict__ cosb,
    const float* __restrict__ sinb) {
  const long row = blockIdx.x;  // b*L + l
  const float* cr = cosb + row * (long)kDH;
  const float* sr = sinb + row * (long)kDH;
  bf16* qr = qkv + row * (long)kQKV;
  bf16* kr = qr + kD;
  const int t = threadIdx.x;
#pragma unroll
  for (int it = 0; it < 4; ++it) {
    const int p = it * 256 + t;  // 0..1023 pair index
    const int h = p >> 6, i = p & 63;
    const int i0 = h * kDH + i, i1 = i0 + 64;
    const float c0 = cr[i], s0 = sr[i], c1 = cr[i + 64], s1 = sr[i + 64];
    const float q0 = (float)qr[i0], q1 = (float)qr[i1];
    qr[i0] = (bf16)(q0 * c0 - q1 * s0);
    qr[i1] = (bf16)(q1 * c1 + q0 * s1);
    const float k0 = (float)kr[i0], k1 = (float)kr[i1];
    kr[i0] = (bf16)(k0 * c0 - k1 * s0);
    kr[i1] = (bf16)(k1 * c1 + k0 * s1);
  }
}

// ---------------------------------------------------------------------------
// v (rows B*L, ld 6144, col offset 4096) -> vT (B,H,DH,L) bf16
// ---------------------------------------------------------------------------
__global__ __launch_bounds__(256) void transpose_v_kernel(
    const bf16* __restrict__ qkv, bf16* __restrict__ vT) {
  __shared__ bf16 tile[32][33];
  const int z = blockIdx.z, b = z / kH, h = z % kH;
  const bf16* src = qkv + (long)b * kL * kQKV + 2 * kD + h * kDH; // [l][d]
  bf16* dst = vT + (long)z * kDH * kL;                            // [d][l]
  const int l0 = blockIdx.x * 32, d0 = blockIdx.y * 32;
  const int tx = threadIdx.x & 31, ty = threadIdx.x >> 5;
  for (int r = ty; r < 32; r += 8)
    tile[r][tx] = src[(long)(l0 + r) * kQKV + d0 + tx];
  __syncthreads();
  for (int r = ty; r < 32; r += 8)
    dst[(long)(d0 + r) * kL + l0 + tx] = tile[tx][r];
}

// ---------------------------------------------------------------------------
// Row softmax over L=1024 f32, in-place (d_out attn region).
// ---------------------------------------------------------------------------
__global__ __launch_bounds__(256) void softmax_kernel(float* __restrict__ attn) {
  const long row = blockIdx.x;
  float* r = attn + row * (long)kL;
  const int t = threadIdx.x;
  float4 v = *(float4*)(r + t * 4);

  __shared__ float red[4];
  float m = fmaxf(fmaxf(v.x, v.y), fmaxf(v.z, v.w));
  for (int off = 32; off > 0; off >>= 1) m = fmaxf(m, __shfl_down(m, off));
  if ((t & 63) == 0) red[t >> 6] = m;
  __syncthreads();
  m = fmaxf(fmaxf(red[0], red[1]), fmaxf(red[2], red[3]));

  v.x = expf(v.x - m); v.y = expf(v.y - m);
  v.z = expf(v.z - m); v.w = expf(v.w - m);
  float s = v.x + v.y + v.z + v.w;
  __syncthreads();
  for (int off = 32; off > 0; off >>= 1) s += __shfl_down(s, off);
  if ((t & 63) == 0) red[t >> 6] = s;
  __syncthreads();
  s = red[0] + red[1] + red[2] + red[3];
  const float inv = 1.0f / s;
  v.x *= inv; v.y *= inv; v.z *= inv; v.w *= inv;
  *(float4*)(r + t * 4) = v;
}

// ---------------------------------------------------------------------------
// GEMM: C[M][N] = epi( scale * (A[M][K] * W[N][K]^T) )
// BM=128, BK template (32|64), 4 waves (2x2), per-wave 64 x NF*16, BN=32*NF.
// Row-major LDS tiles [rows][BK]; staging linear & lane-coalesced.
// XCD-aware bijective tile swizzle (m204) for L2 panel reuse.
// AF32 (BK=32 only): A f32 converted to bf16 in VGPRs during staging.
// ---------------------------------------------------------------------------
enum { EPI_NONE = 0, EPI_ADD = 1, EPI_MASK = 2, EPI_SILU = 3, EPI_OUTADD = 4 };

template <typename OutT, int EPI, bool AF32, int NF, int BK>
__device__ __forceinline__ void gemm_body(
    const void* __restrict__ Ap, long sAo, long sAi, int lda,
    const bf16* __restrict__ Bp, long sBo, long sBi, int ldb,
    OutT* Cp, long sCo, long sCi, int ldc,
    const void* Ep, long sEo, long sEi, int lde,
    float scale, int Hdiv, int M, int N, int K) {
  constexpr int BN = 32 * NF;          // 128 (NF=4) or 64 (NF=2)
  constexpr int KK = BK / 32;          // K-subtiles per staged tile
  constexpr int RCH = BK / 8;          // 16B chunks per row
  constexpr int ACH = 128 * RCH;
  constexpr int BCH = BN * RCH;
  static_assert(!AF32 || BK == 32, "AF32 path requires BK=32");

  const int z = blockIdx.z;
  const int zo = z / Hdiv, zi = z % Hdiv;

  const bf16* A = nullptr;
  const float* Af = nullptr;
  if constexpr (AF32) Af = (const float*)Ap + zo * sAo + zi * sAi;
  else                A  = (const bf16*)Ap + zo * sAo + zi * sAi;
  const bf16* Bw = Bp + zo * sBo + zi * sBi;
  OutT* C = Cp + zo * sCo + zi * sCi;

  __shared__ __align__(16) bf16 lsA[128 * BK];
  __shared__ __align__(16) bf16 lsB[BN * BK];

  const int t = threadIdx.x;

  // XCD-aware bijective swizzle of the (bx,by) tile index (T1 / m204).
  const int gx = gridDim.x;
  int flat = blockIdx.y * gx + blockIdx.x;
  {
    const int nwg = gx * gridDim.y;
    const int q = nwg >> 3, r = nwg & 7;
    const int xcd = flat & 7, lin = flat >> 3;
    flat = (xcd < r ? xcd * (q + 1) : r * (q + 1) + (xcd - r) * q) + lin;
  }
  const int m0 = (flat / gx) * 128, n0 = (flat % gx) * BN;

  const int wave = t >> 6, lane = t & 63;
  const int wm = (wave >> 1) * 64, wn = (wave & 1) * (NF * 16);
  const int lr = lane & 15, lg = lane >> 4;

  f32x4 acc[4][NF] = {};

  for (int k0 = 0; k0 < K; k0 += BK) {
    __syncthreads();  // prior iter's fragment reads done before restage
    if constexpr (AF32) {
#pragma unroll
      for (int c = 0; c < 2; ++c) {
        const int id = c * 256 + t;
        const int row = id >> 2, col = (id & 3) * 8;
        const float* src = Af + (long)(m0 + row) * lda + k0 + col;
        const float4 u0 = *(const float4*)src;
        const float4 u1 = *(const float4*)(src + 4);
        bf16x8 wv;
        wv[0] = (bf16)u0.x; wv[1] = (bf16)u0.y; wv[2] = (bf16)u0.z; wv[3] = (bf16)u0.w;
        wv[4] = (bf16)u1.x; wv[5] = (bf16)u1.y; wv[6] = (bf16)u1.z; wv[7] = (bf16)u1.w;
        *(bf16x8*)&lsA[id * 8] = wv;
        if (NF == 4 || c == 0) {  // stage B (BN*4 chunks)
          gload_lds16(Bw + (long)(n0 + row) * ldb + k0 + col, &lsB[id * 8]);
        }
      }
    } else {
#pragma unroll
      for (int c = 0; c < (ACH + BCH) / 256; ++c) {
        const int id = c * 256 + t;
        if (id < ACH) {
          const int row = id / RCH, col = (id % RCH) * 8;
          gload_lds16(A + (long)(m0 + row) * lda + k0 + col, &lsA[id * 8]);
        } else {
          const int fid = id - ACH;
          const int row = fid / RCH, col = (fid % RCH) * 8;
          gload_lds16(Bw + (long)(n0 + row) * ldb + k0 + col, &lsB[fid * 8]);
        }
      }
    }
    __syncthreads();  // drains vmcnt+lgkmcnt before any wave reads staged data

    bf16x8 af[KK][4], bfr[KK][NF];
#pragma unroll
    for (int kk = 0; kk < KK; ++kk) {
#pragma unroll
      for (int i = 0; i < 4; ++i)
        af[kk][i] = *(const bf16x8*)&lsA[(wm + i * 16 + lr) * BK + kk * 32 + lg * 8];
#pragma unroll
      for (int j = 0; j < NF; ++j)
        bfr[kk][j] = *(const bf16x8*)&lsB[(wn + j * 16 + lr) * BK + kk * 32 + lg * 8];
    }
#pragma unroll
    for (int kk = 0; kk < KK; ++kk)
#pragma unroll
      for (int i = 0; i < 4; ++i)
#pragma unroll
        for (int j = 0; j < NF; ++j)
          acc[i][j] = __builtin_amdgcn_mfma_f32_16x16x32_bf16(
              af[kk][i], bfr[kk][j], acc[i][j], 0, 0, 0);
  }

  // epilogue: lane holds C[wm+i*16+lg*4+r][wn+j*16+lr] in acc[i][j][r]
  const float* Ef = (const float*)Ep;
  const bf16* Eb = (const bf16*)Ep;
  long ebase = 0;
  if constexpr (EPI == EPI_ADD || EPI == EPI_MASK || EPI == EPI_SILU)
    ebase = zo * sEo + zi * sEi;
#pragma unroll
  for (int i = 0; i < 4; ++i) {
#pragma unroll
    for (int j = 0; j < NF; ++j) {
      const int col = n0 + wn + j * 16 + lr;
#pragma unroll
      for (int r = 0; r < 4; ++r) {
        const int rowi = m0 + wm + i * 16 + lg * 4 + r;
        float val = acc[i][j][r] * scale;
        const long idx = (long)rowi * ldc + col;
        const long eidx = ebase + (long)rowi * lde + col;
        if constexpr (EPI == EPI_ADD || EPI == EPI_MASK) val += Ef[eidx];
        if constexpr (EPI == EPI_SILU) {
          const float g = (float)Eb[eidx];
          val = (g / (1.0f + expf(-g))) * val;
        }
        if constexpr (EPI == EPI_OUTADD)
          val += ((float*)Cp)[zo * sCo + zi * sCi + idx];
        C[idx] = (OutT)val;
      }
    }
  }
}

#define GEMM_ARGS                                                        \
  const void* __restrict__ Ap, long sAo, long sAi, int lda,              \
  const bf16* __restrict__ Bp, long sBo, long sBi, int ldb,              \
  void* Cp, long sCo, long sCi, int ldc,                                 \
  const void* Ep, long sEo, long sEi, int lde,                           \
  float scale, int Hdiv, int M, int N, int K
#define GEMM_PASS Ap, sAo, sAi, lda, Bp, sBo, sBi, ldb, (OUT_T*)Cp, sCo, \
  sCi, ldc, Ep, sEo, sEi, lde, scale, Hdiv, M, N, K

#define DEF_GEMM(NAME, OUT_TY, EPI_V, AF32_V, NF_V, BK_V)                \
  __global__ __launch_bounds__(256) void NAME(GEMM_ARGS) {               \
    using OUT_T = OUT_TY;                                                \
    gemm_body<OUT_T, EPI_V, AF32_V, NF_V, BK_V>(GEMM_PASS);              \
  }

DEF_GEMM(gemm_qkv,    bf16,  EPI_NONE,   false, 4, 64)  // BN=128, grid 1536
DEF_GEMM(gemm_scores, float, EPI_MASK,   false, 4, 64)  // BN=128, grid 4096
DEF_GEMM(gemm_ctx,    bf16,  EPI_NONE,   true,  2, 32)  // BN=64,  grid 1024
DEF_GEMM(gemm_oproj,  float, EPI_ADD,    false, 2, 64)  // BN=64,  grid 1024
DEF_GEMM(gemm_gate,   bf16,  EPI_NONE,   false, 4, 64)  // BN=128, grid 2048
DEF_GEMM(gemm_up,     bf16,  EPI_SILU,   false, 4, 64)  // BN=128, grid 2048
DEF_GEMM(gemm_down,   float, EPI_OUTADD, false, 2, 64)  // BN=64,  grid 1024

// ---------------------------------------------------------------------------
// Host launcher
// ---------------------------------------------------------------------------
extern "C" void kernel_launch(void* const* d_in, const int* in_sizes, int n_in,
                              void* d_out, int out_size, void* d_ws,
                              size_t ws_size, hipStream_t stream) {
  (void)in_sizes; (void)n_in; (void)out_size; (void)ws_size;

  const float* hidden = (const float*)d_in[0];
  const float* mask   = (const float*)d_in[1];
  const float* cosb   = (const float*)d_in[2];
  const float* sinb   = (const float*)d_in[3];
  const float* q_w    = (const float*)d_in[4];
  const float* k_w    = (const float*)d_in[5];
  const float* v_w    = (const float*)d_in[6];
  const float* o_w    = (const float*)d_in[7];
  const float* gate_w = (const float*)d_in[8];
  const float* up_w   = (const float*)d_in[9];
  const float* down_w = (const float*)d_in[10];
  const float* ln1    = (const float*)d_in[11];
  const float* ln2    = (const float*)d_in[12];

  float* out  = (float*)d_out;             // (B,L,D): h1 then final
  float* attn = out + (long)kB * kL * kD;  // (B,H,L,L)

  // workspace layout (bf16 elements), ~201 MB
  bf16* wsb = (bf16*)d_ws;
  long off = 0;
  bf16* WQKV = wsb + off; off += 3L * kD * kD;         // q,k,v weights stacked
  bf16* WO   = wsb + off; off += (long)kD * kD;
  bf16* WBIG = wsb + off; off += (long)kI * kD;        // gate/up/down JIT
  bf16* HBF  = wsb + off; off += (long)kB * kL * kD;   // h (ln1), later ctx
  bf16* QKV  = wsb + off; off += (long)kB * kL * kQKV; // fused qkv; later h2
  bf16* GBUF = wsb + off; off += (long)kB * kL * kI;   // vT, then gate/mlp

  const long DD = (long)kD * kD;
  const long ID = (long)kI * kD;
  const int  ML = kB * kL;  // 4096

  // 1. cast attention weights (q,k,v stacked -> WQKV)
  cast_f32_bf16_kernel<<<dim3((int)(DD / 1024)), 256, 0, stream>>>(q_w, WQKV, DD);
  cast_f32_bf16_kernel<<<dim3((int)(DD / 1024)), 256, 0, stream>>>(k_w, WQKV + DD, DD);
  cast_f32_bf16_kernel<<<dim3((int)(DD / 1024)), 256, 0, stream>>>(v_w, WQKV + 2 * DD, DD);
  cast_f32_bf16_kernel<<<dim3((int)(DD / 1024)), 256, 0, stream>>>(o_w, WO, DD);

  // 2. rmsnorm1: hidden -> HBF (bf16)
  rmsnorm_kernel<<<ML, 256, 0, stream>>>(hidden, ln1, HBF);

  // 3. fused qkv projection: (4096 x 6144 x 2048) -> QKV (ld 6144)
  gemm_qkv<<<dim3(kQKV / 128, ML / 128, 1), 256, 0, stream>>>(
      HBF, 0, 0, kD, WQKV, 0, 0, kD, QKV, 0, 0, kQKV,
      nullptr, 0, 0, 0, 1.0f, 1, ML, kQKV, kD);

  // 4. RoPE in-place on q,k
  rope_kernel<<<ML, 256, 0, stream>>>(QKV, cosb, sinb);

  // 5. v -> vT (B,H,DH,L) into GBUF
  transpose_v_kernel<<<dim3(kL / 32, kDH / 32, kB * kH), 256, 0, stream>>>(QKV, GBUF);

  // 6. scores = q k^T / sqrt(DH) + mask -> attn (f32)
  gemm_scores<<<dim3(kL / 128, kL / 128, kB * kH), 256, 0, stream>>>(
      QKV, (long)kL * kQKV, kDH, kQKV,
      QKV + kD, (long)kL * kQKV, kDH, kQKV,
      attn, (long)kH * kL * kL, (long)kL * kL, kL,
      mask, (long)kL * kL, 0, kL,
      kScoreScale, kH, kL, kL, kDH);

  // 7. softmax rows in-place
  softmax_kernel<<<kB * kH * kL, 256, 0, stream>>>(attn);

  // 8. ctx = attn @ vT^T (A f32, VALU-converted during staging) -> HBF
  gemm_ctx<<<dim3(kDH / 64, kL / 128, kB * kH), 256, 0, stream>>>(
      attn, (long)kH * kL * kL, (long)kL * kL, kL,
      GBUF, (long)kH * kDH * kL, (long)kDH * kL, kL,
      HBF, (long)kL * kD, kDH, kD,
      nullptr, 0, 0, 0, 1.0f, kH, kL, kDH, kL);

  // 9. h1 = hidden + ctx @ o_w^T -> out (f32)
  gemm_oproj<<<dim3(kD / 64, ML / 128, 1), 256, 0, stream>>>(
      HBF, 0, 0, kD, WO, 0, 0, kD, out, 0, 0, kD,
      hidden, 0, 0, kD, 1.0f, 1, ML, kD, kD);

  // 10. rmsnorm2: h1 -> QKV region (h2 bf16, compact ld=kD)
  bf16* H2 = QKV;
  rmsnorm_kernel<<<ML, 256, 0, stream>>>(out, ln2, H2);

  // 11. gate = h2 @ gate_w^T -> GBUF
  cast_f32_bf16_kernel<<<dim3((int)(ID / 1024)), 256, 0, stream>>>(gate_w, WBIG, ID);
  gemm_gate<<<dim3(kI / 128, ML / 128, 1), 256, 0, stream>>>(
      H2, 0, 0, kD, WBIG, 0, 0, kD, GBUF, 0, 0, kI,
      nullptr, 0, 0, 0, 1.0f, 1, ML, kI, kD);

  // 12. mlp = silu(gate) * (h2 @ up_w^T) -> GBUF in-place
  cast_f32_bf16_kernel<<<dim3((int)(ID / 1024)), 256, 0, stream>>>(up_w, WBIG, ID);
  gemm_up<<<dim3(kI / 128, ML / 128, 1), 256, 0, stream>>>(
      H2, 0, 0, kD, WBIG, 0, 0, kD, GBUF, 0, 0, kI,
      GBUF, 0, 0, kI, 1.0f, 1, ML, kI, kD);

  // 13. out = h1 + mlp @ down_w^T (h1 already in out)
  cast_f32_bf16_kernel<<<dim3((int)(ID / 1024)), 256, 0, stream>>>(down_w, WBIG, ID);
  gemm_down<<<dim3(kD / 64, ML / 128, 1), 256, 0, stream>>>(
      GBUF, 0, 0, kI, WBIG, 0, 0, kI, out, 0, 0, kD,
      nullptr, 0, 0, 0, 1.0f, 1, ML, kD, kI);
}

// Round 5
// 1147.943 us; speedup vs baseline: 1.1903x; 1.1903x over previous
//
#include <hip/hip_runtime.h>

// ---------------------------------------------------------------------------
// LlamaDecoderLayer forward on MI355X (gfx950).
// B=4, L=1024, D=2048, H=16, I=8192, DH=128.
// Outputs (f32): out (B,L,D) then attn (B,H,L,L), concatenated in d_out.
// ---------------------------------------------------------------------------

typedef __bf16 bf16;
typedef __bf16 bf16x8 __attribute__((ext_vector_type(8)));
typedef __bf16 bf16x4 __attribute__((ext_vector_type(4)));
typedef float  f32x4  __attribute__((ext_vector_type(4)));

constexpr int   kB  = 4;
constexpr int   kL  = 1024;
constexpr int   kD  = 2048;
constexpr int   kH  = 16;
constexpr int   kI  = 8192;
constexpr int   kDH = 128;
constexpr int   kQKV = 3 * kD;  // 6144
constexpr float kEps = 1e-6f;
constexpr float kScoreScale = 0.08838834764831845f; // 1/sqrt(128)

typedef __attribute__((address_space(1))) void gvoid_t;
typedef __attribute__((address_space(3))) void lvoid_t;

// async global->LDS, 16B per lane; LDS dest linear in lane order.
// Adjacent lanes MUST hit adjacent global addresses (round-2 lesson).
__device__ __forceinline__ void gload_lds16(const void* g, void* l) {
  __builtin_amdgcn_global_load_lds((gvoid_t*)g, (lvoid_t*)l, 16, 0, 0);
}

// ---------------------------------------------------------------------------
// f32 -> bf16 cast (vectorized). n must be a multiple of 4.
// ---------------------------------------------------------------------------
__global__ __launch_bounds__(256) void cast_f32_bf16_kernel(
    const float* __restrict__ x, bf16* __restrict__ y, long n) {
  long i = ((long)blockIdx.x * 256 + threadIdx.x) * 4;
  long stride = (long)gridDim.x * 256 * 4;
  for (; i < n; i += stride) {
    const float4 v = *reinterpret_cast<const float4*>(x + i);
    bf16x4 o;
    o[0] = (bf16)v.x; o[1] = (bf16)v.y; o[2] = (bf16)v.z; o[3] = (bf16)v.w;
    *reinterpret_cast<bf16x4*>(y + i) = o;
  }
}

// ---------------------------------------------------------------------------
// RMSNorm: one block per row of D=2048 f32; writes bf16 (row stride kD).
// ---------------------------------------------------------------------------
__global__ __launch_bounds__(256) void rmsnorm_kernel(
    const float* __restrict__ x, const float* __restrict__ w,
    bf16* __restrict__ out) {
  const long row = blockIdx.x;
  const float* xr = x + row * (long)kD;
  bf16* orow = out + row * (long)kD;
  const int t = threadIdx.x;

  float4 v0 = *(const float4*)(xr + t * 8);
  float4 v1 = *(const float4*)(xr + t * 8 + 4);
  float ss = v0.x * v0.x + v0.y * v0.y + v0.z * v0.z + v0.w * v0.w +
             v1.x * v1.x + v1.y * v1.y + v1.z * v1.z + v1.w * v1.w;

  __shared__ float red[4];
  for (int off = 32; off > 0; off >>= 1) ss += __shfl_down(ss, off);
  if ((t & 63) == 0) red[t >> 6] = ss;
  __syncthreads();
  const float tot = red[0] + red[1] + red[2] + red[3];
  const float rs = rsqrtf(tot / (float)kD + kEps);

  float4 w0 = *(const float4*)(w + t * 8);
  float4 w1 = *(const float4*)(w + t * 8 + 4);
  bf16x8 o;
  o[0] = (bf16)(v0.x * rs * w0.x); o[1] = (bf16)(v0.y * rs * w0.y);
  o[2] = (bf16)(v0.z * rs * w0.z); o[3] = (bf16)(v0.w * rs * w0.w);
  o[4] = (bf16)(v1.x * rs * w1.x); o[5] = (bf16)(v1.y * rs * w1.y);
  o[6] = (bf16)(v1.z * rs * w1.z); o[7] = (bf16)(v1.w * rs * w1.w);
  *(bf16x8*)(orow + t * 8) = o;
}

// ---------------------------------------------------------------------------
// RoPE in-place on qkv buffer (bf16, rows = B*L, ld = 6144).
// ---------------------------------------------------------------------------
__global__ __launch_bounds__(256) void rope_kernel(
    bf16* __restrict__ qkv, const float* __restrict__ cosb,
    const float* __restrict__ sinb) {
  const long row = blockIdx.x;  // b*L + l
  const float* cr = cosb + row * (long)kDH;
  const float* sr = sinb + row * (long)kDH;
  bf16* qr = qkv + row * (long)kQKV;
  bf16* kr = qr + kD;
  const int t = threadIdx.x;
#pragma unroll
  for (int it = 0; it < 4; ++it) {
    const int p = it * 256 + t;  // 0..1023 pair index
    const int h = p >> 6, i = p & 63;
    const int i0 = h * kDH + i, i1 = i0 + 64;
    const float c0 = cr[i], s0 = sr[i], c1 = cr[i + 64], s1 = sr[i + 64];
    const float q0 = (float)qr[i0], q1 = (float)qr[i1];
    qr[i0] = (bf16)(q0 * c0 - q1 * s0);
    qr[i1] = (bf16)(q1 * c1 + q0 * s1);
    const float k0 = (float)kr[i0], k1 = (float)kr[i1];
    kr[i0] = (bf16)(k0 * c0 - k1 * s0);
    kr[i1] = (bf16)(k1 * c1 + k0 * s1);
  }
}

// ---------------------------------------------------------------------------
// v (rows B*L, ld 6144, col offset 4096) -> vT (B,H,DH,L) bf16
// ---------------------------------------------------------------------------
__global__ __launch_bounds__(256) void transpose_v_kernel(
    const bf16* __restrict__ qkv, bf16* __restrict__ vT) {
  __shared__ bf16 tile[32][33];
  const int z = blockIdx.z, b = z / kH, h = z % kH;
  const bf16* src = qkv + (long)b * kL * kQKV + 2 * kD + h * kDH; // [l][d]
  bf16* dst = vT + (long)z * kDH * kL;                            // [d][l]
  const int l0 = blockIdx.x * 32, d0 = blockIdx.y * 32;
  const int tx = threadIdx.x & 31, ty = threadIdx.x >> 5;
  for (int r = ty; r < 32; r += 8)
    tile[r][tx] = src[(long)(l0 + r) * kQKV + d0 + tx];
  __syncthreads();
  for (int r = ty; r < 32; r += 8)
    dst[(long)(d0 + r) * kL + l0 + tx] = tile[tx][r];
}

// ---------------------------------------------------------------------------
// Row softmax over L=1024 f32, in-place (d_out attn region).
// ---------------------------------------------------------------------------
__global__ __launch_bounds__(256) void softmax_kernel(float* __restrict__ attn) {
  const long row = blockIdx.x;
  float* r = attn + row * (long)kL;
  const int t = threadIdx.x;
  float4 v = *(float4*)(r + t * 4);

  __shared__ float red[4];
  float m = fmaxf(fmaxf(v.x, v.y), fmaxf(v.z, v.w));
  for (int off = 32; off > 0; off >>= 1) m = fmaxf(m, __shfl_down(m, off));
  if ((t & 63) == 0) red[t >> 6] = m;
  __syncthreads();
  m = fmaxf(fmaxf(red[0], red[1]), fmaxf(red[2], red[3]));

  v.x = expf(v.x - m); v.y = expf(v.y - m);
  v.z = expf(v.z - m); v.w = expf(v.w - m);
  float s = v.x + v.y + v.z + v.w;
  __syncthreads();
  for (int off = 32; off > 0; off >>= 1) s += __shfl_down(s, off);
  if ((t & 63) == 0) red[t >> 6] = s;
  __syncthreads();
  s = red[0] + red[1] + red[2] + red[3];
  const float inv = 1.0f / s;
  v.x *= inv; v.y *= inv; v.z *= inv; v.w *= inv;
  *(float4*)(r + t * 4) = v;
}

// ---------------------------------------------------------------------------
// GEMM: C[M][N] = epi( scale * (A[M][K] * W[N][K]^T) )
// BM=128, BK=32, 4 waves (2x2), per-wave 64 x NF*16, BN=32*NF.
// SINGLE-BARRIER DOUBLE-BUFFERED K-loop (T3 minimum 2-phase): stage tile
// t+1 into buf^1 BEFORE computing tile t from buf; one __syncthreads per
// K-step (its implicit vmcnt(0)+lgkmcnt(0) drain makes buf^1 ready and
// orders the frag reads of buf before its restage next iter).
// Row-major LDS tiles [rows][32]; staging linear & lane-coalesced.
// EPI_MASK: analytic causal mask (col>row -> -1e9), no mask tensor read.
// AF32: A f32 -> bf16 via VGPR during staging (ds_write path).
// ---------------------------------------------------------------------------
enum { EPI_NONE = 0, EPI_ADD = 1, EPI_MASK = 2, EPI_SILU = 3, EPI_OUTADD = 4 };

template <typename OutT, int EPI, bool AF32, int NF>
__device__ __forceinline__ void gemm_body(
    const void* __restrict__ Ap, long sAo, long sAi, int lda,
    const bf16* __restrict__ Bp, long sBo, long sBi, int ldb,
    OutT* Cp, long sCo, long sCi, int ldc,
    const void* Ep, long sEo, long sEi, int lde,
    float scale, int Hdiv, int M, int N, int K) {
  constexpr int BN = 32 * NF;          // 128 (NF=4) or 64 (NF=2)
  constexpr int ACH = 512;             // A 16B chunks per k-step (128*32/8)
  constexpr int BCH = BN * 4;          // B 16B chunks per k-step

  const int z = blockIdx.z;
  const int zo = z / Hdiv, zi = z % Hdiv;

  const bf16* A = nullptr;
  const float* Af = nullptr;
  if constexpr (AF32) Af = (const float*)Ap + zo * sAo + zi * sAi;
  else                A  = (const bf16*)Ap + zo * sAo + zi * sAi;
  const bf16* Bw = Bp + zo * sBo + zi * sBi;
  OutT* C = Cp + zo * sCo + zi * sCi;

  __shared__ __align__(16) bf16 lsA[2][128 * 32];
  __shared__ __align__(16) bf16 lsB[2][BN * 32];

  const int t = threadIdx.x;
  const int m0 = blockIdx.y * 128, n0 = blockIdx.x * BN;
  const int wave = t >> 6, lane = t & 63;
  const int wm = (wave >> 1) * 64, wn = (wave & 1) * (NF * 16);
  const int lr = lane & 15, lg = lane >> 4;

  f32x4 acc[4][NF] = {};

  auto stage = [&](int buf, int k0) {
    if constexpr (AF32) {
#pragma unroll
      for (int c = 0; c < 2; ++c) {
        const int id = c * 256 + t;
        const int row = id >> 2, col = (id & 3) * 8;
        const float* src = Af + (long)(m0 + row) * lda + k0 + col;
        const float4 u0 = *(const float4*)src;
        const float4 u1 = *(const float4*)(src + 4);
        bf16x8 wv;
        wv[0] = (bf16)u0.x; wv[1] = (bf16)u0.y; wv[2] = (bf16)u0.z; wv[3] = (bf16)u0.w;
        wv[4] = (bf16)u1.x; wv[5] = (bf16)u1.y; wv[6] = (bf16)u1.z; wv[7] = (bf16)u1.w;
        *(bf16x8*)&lsA[buf][id * 8] = wv;
        if (NF == 4 || c == 0)
          gload_lds16(Bw + (long)(n0 + row) * ldb + k0 + col, &lsB[buf][id * 8]);
      }
    } else {
#pragma unroll
      for (int c = 0; c < (ACH + BCH) / 256; ++c) {
        const int id = c * 256 + t;
        if (id < ACH) {
          const int row = id >> 2, col = (id & 3) * 8;
          gload_lds16(A + (long)(m0 + row) * lda + k0 + col, &lsA[buf][id * 8]);
        } else {
          const int fid = id - ACH;
          const int row = fid >> 2, col = (fid & 3) * 8;
          gload_lds16(Bw + (long)(n0 + row) * ldb + k0 + col, &lsB[buf][fid * 8]);
        }
      }
    }
  };

  auto compute = [&](int buf) {
    bf16x8 af[4], bfr[NF];
#pragma unroll
    for (int i = 0; i < 4; ++i)
      af[i] = *(const bf16x8*)&lsA[buf][(wm + i * 16 + lr) * 32 + lg * 8];
#pragma unroll
    for (int j = 0; j < NF; ++j)
      bfr[j] = *(const bf16x8*)&lsB[buf][(wn + j * 16 + lr) * 32 + lg * 8];
#pragma unroll
    for (int i = 0; i < 4; ++i)
#pragma unroll
      for (int j = 0; j < NF; ++j)
        acc[i][j] = __builtin_amdgcn_mfma_f32_16x16x32_bf16(af[i], bfr[j],
                                                            acc[i][j], 0, 0, 0);
  };

  // prologue: fill buf 0, drain, barrier.
  stage(0, 0);
  __syncthreads();

  int cur = 0;
  for (int k0 = 0; k0 < K - 32; k0 += 32) {
    stage(cur ^ 1, k0 + 32);  // issue next tile's loads first (overlap)
    compute(cur);             // ds_read + MFMA on current tile
    __syncthreads();          // implicit vmcnt(0)+lgkmcnt(0): buf^1 ready,
    cur ^= 1;                 // and our reads of buf done before restage
  }
  compute(cur);               // final tile, no prefetch

  // epilogue: lane holds C[wm+i*16+lg*4+r][wn+j*16+lr] in acc[i][j][r]
  const float* Ef = (const float*)Ep;
  const bf16* Eb = (const bf16*)Ep;
  long ebase = 0;
  if constexpr (EPI == EPI_ADD || EPI == EPI_SILU)
    ebase = zo * sEo + zi * sEi;
#pragma unroll
  for (int i = 0; i < 4; ++i) {
#pragma unroll
    for (int j = 0; j < NF; ++j) {
      const int col = n0 + wn + j * 16 + lr;
#pragma unroll
      for (int r = 0; r < 4; ++r) {
        const int rowi = m0 + wm + i * 16 + lg * 4 + r;
        float val = acc[i][j][r] * scale;
        const long idx = (long)rowi * ldc + col;
        if constexpr (EPI == EPI_MASK) {
          if (col > rowi) val += -1.0e9f;  // exact causal mask values
        }
        if constexpr (EPI == EPI_ADD) {
          val += Ef[ebase + (long)rowi * lde + col];
        }
        if constexpr (EPI == EPI_SILU) {
          const float g = (float)Eb[ebase + (long)rowi * lde + col];
          val = (g / (1.0f + expf(-g))) * val;
        }
        if constexpr (EPI == EPI_OUTADD)
          val += ((float*)Cp)[zo * sCo + zi * sCi + idx];
        C[idx] = (OutT)val;
      }
    }
  }
}

#define GEMM_ARGS                                                        \
  const void* __restrict__ Ap, long sAo, long sAi, int lda,              \
  const bf16* __restrict__ Bp, long sBo, long sBi, int ldb,              \
  void* Cp, long sCo, long sCi, int ldc,                                 \
  const void* Ep, long sEo, long sEi, int lde,                           \
  float scale, int Hdiv, int M, int N, int K
#define GEMM_PASS Ap, sAo, sAi, lda, Bp, sBo, sBi, ldb, (OUT_T*)Cp, sCo, \
  sCi, ldc, Ep, sEo, sEi, lde, scale, Hdiv, M, N, K

#define DEF_GEMM(NAME, OUT_TY, EPI_V, AF32_V, NF_V)                      \
  __global__ __launch_bounds__(256) void NAME(GEMM_ARGS) {               \
    using OUT_T = OUT_TY;                                                \
    gemm_body<OUT_T, EPI_V, AF32_V, NF_V>(GEMM_PASS);                    \
  }

DEF_GEMM(gemm_qkv,    bf16,  EPI_NONE,   false, 4)  // BN=128, grid 1536
DEF_GEMM(gemm_scores, float, EPI_MASK,   false, 4)  // BN=128, grid 4096
DEF_GEMM(gemm_ctx,    bf16,  EPI_NONE,   true,  2)  // BN=64,  grid 1024
DEF_GEMM(gemm_oproj,  float, EPI_ADD,    false, 2)  // BN=64,  grid 1024
DEF_GEMM(gemm_gate,   bf16,  EPI_NONE,   false, 4)  // BN=128, grid 2048
DEF_GEMM(gemm_up,     bf16,  EPI_SILU,   false, 4)  // BN=128, grid 2048
DEF_GEMM(gemm_down,   float, EPI_OUTADD, false, 2)  // BN=64,  grid 1024

// ---------------------------------------------------------------------------
// Host launcher
// ---------------------------------------------------------------------------
extern "C" void kernel_launch(void* const* d_in, const int* in_sizes, int n_in,
                              void* d_out, int out_size, void* d_ws,
                              size_t ws_size, hipStream_t stream) {
  (void)in_sizes; (void)n_in; (void)out_size; (void)ws_size;

  const float* hidden = (const float*)d_in[0];
  const float* cosb   = (const float*)d_in[2];
  const float* sinb   = (const float*)d_in[3];
  const float* q_w    = (const float*)d_in[4];
  const float* k_w    = (const float*)d_in[5];
  const float* v_w    = (const float*)d_in[6];
  const float* o_w    = (const float*)d_in[7];
  const float* gate_w = (const float*)d_in[8];
  const float* up_w   = (const float*)d_in[9];
  const float* down_w = (const float*)d_in[10];
  const float* ln1    = (const float*)d_in[11];
  const float* ln2    = (const float*)d_in[12];

  float* out  = (float*)d_out;             // (B,L,D): h1 then final
  float* attn = out + (long)kB * kL * kD;  // (B,H,L,L)

  // workspace layout (bf16 elements), ~201 MB
  bf16* wsb = (bf16*)d_ws;
  long off = 0;
  bf16* WQKV = wsb + off; off += 3L * kD * kD;         // q,k,v weights stacked
  bf16* WO   = wsb + off; off += (long)kD * kD;
  bf16* WBIG = wsb + off; off += (long)kI * kD;        // gate/up/down JIT
  bf16* HBF  = wsb + off; off += (long)kB * kL * kD;   // h (ln1), later ctx
  bf16* QKV  = wsb + off; off += (long)kB * kL * kQKV; // fused qkv; later h2
  bf16* GBUF = wsb + off; off += (long)kB * kL * kI;   // vT, then gate/mlp

  const long DD = (long)kD * kD;
  const long ID = (long)kI * kD;
  const int  ML = kB * kL;  // 4096

  // 1. cast attention weights (q,k,v stacked -> WQKV)
  cast_f32_bf16_kernel<<<dim3((int)(DD / 1024)), 256, 0, stream>>>(q_w, WQKV, DD);
  cast_f32_bf16_kernel<<<dim3((int)(DD / 1024)), 256, 0, stream>>>(k_w, WQKV + DD, DD);
  cast_f32_bf16_kernel<<<dim3((int)(DD / 1024)), 256, 0, stream>>>(v_w, WQKV + 2 * DD, DD);
  cast_f32_bf16_kernel<<<dim3((int)(DD / 1024)), 256, 0, stream>>>(o_w, WO, DD);

  // 2. rmsnorm1: hidden -> HBF (bf16)
  rmsnorm_kernel<<<ML, 256, 0, stream>>>(hidden, ln1, HBF);

  // 3. fused qkv projection: (4096 x 6144 x 2048) -> QKV (ld 6144)
  gemm_qkv<<<dim3(kQKV / 128, ML / 128, 1), 256, 0, stream>>>(
      HBF, 0, 0, kD, WQKV, 0, 0, kD, QKV, 0, 0, kQKV,
      nullptr, 0, 0, 0, 1.0f, 1, ML, kQKV, kD);

  // 4. RoPE in-place on q,k
  rope_kernel<<<ML, 256, 0, stream>>>(QKV, cosb, sinb);

  // 5. v -> vT (B,H,DH,L) into GBUF
  transpose_v_kernel<<<dim3(kL / 32, kDH / 32, kB * kH), 256, 0, stream>>>(QKV, GBUF);

  // 6. scores = q k^T / sqrt(DH) + causal mask -> attn (f32)
  gemm_scores<<<dim3(kL / 128, kL / 128, kB * kH), 256, 0, stream>>>(
      QKV, (long)kL * kQKV, kDH, kQKV,
      QKV + kD, (long)kL * kQKV, kDH, kQKV,
      attn, (long)kH * kL * kL, (long)kL * kL, kL,
      nullptr, 0, 0, 0,
      kScoreScale, kH, kL, kL, kDH);

  // 7. softmax rows in-place
  softmax_kernel<<<kB * kH * kL, 256, 0, stream>>>(attn);

  // 8. ctx = attn @ vT^T (A f32, VALU-converted during staging) -> HBF
  gemm_ctx<<<dim3(kDH / 64, kL / 128, kB * kH), 256, 0, stream>>>(
      attn, (long)kH * kL * kL, (long)kL * kL, kL,
      GBUF, (long)kH * kDH * kL, (long)kDH * kL, kL,
      HBF, (long)kL * kD, kDH, kD,
      nullptr, 0, 0, 0, 1.0f, kH, kL, kDH, kL);

  // 9. h1 = hidden + ctx @ o_w^T -> out (f32)
  gemm_oproj<<<dim3(kD / 64, ML / 128, 1), 256, 0, stream>>>(
      HBF, 0, 0, kD, WO, 0, 0, kD, out, 0, 0, kD,
      hidden, 0, 0, kD, 1.0f, 1, ML, kD, kD);

  // 10. rmsnorm2: h1 -> QKV region (h2 bf16, compact ld=kD)
  bf16* H2 = QKV;
  rmsnorm_kernel<<<ML, 256, 0, stream>>>(out, ln2, H2);

  // 11. gate = h2 @ gate_w^T -> GBUF
  cast_f32_bf16_kernel<<<dim3((int)(ID / 1024)), 256, 0, stream>>>(gate_w, WBIG, ID);
  gemm_gate<<<dim3(kI / 128, ML / 128, 1), 256, 0, stream>>>(
      H2, 0, 0, kD, WBIG, 0, 0, kD, GBUF, 0, 0, kI,
      nullptr, 0, 0, 0, 1.0f, 1, ML, kI, kD);

  // 12. mlp = silu(gate) * (h2 @ up_w^T) -> GBUF in-place
  cast_f32_bf16_kernel<<<dim3((int)(ID / 1024)), 256, 0, stream>>>(up_w, WBIG, ID);
  gemm_up<<<dim3(kI / 128, ML / 128, 1), 256, 0, stream>>>(
      H2, 0, 0, kD, WBIG, 0, 0, kD, GBUF, 0, 0, kI,
      GBUF, 0, 0, kI, 1.0f, 1, ML, kI, kD);

  // 13. out = h1 + mlp @ down_w^T (h1 already in out)
  cast_f32_bf16_kernel<<<dim3((int)(ID / 1024)), 256, 0, stream>>>(down_w, WBIG, ID);
  gemm_down<<<dim3(kD / 64, ML / 128, 1), 256, 0, stream>>>(
      GBUF, 0, 0, kI, WBIG, 0, 0, kI, out, 0, 0, kD,
      nullptr, 0, 0, 0, 1.0f, 1, ML, kD, kI);
}